// Round 15
// baseline (178.777 us; speedup 1.0000x reference)
//
#include <hip/hip_runtime.h>

#define DI __device__ __forceinline__

typedef unsigned int uint32;
typedef unsigned short u16;
typedef __attribute__((ext_vector_type(8))) short s8v;   // 8 bf16 (4 VGPR)
typedef __attribute__((ext_vector_type(4))) float f4v;   // MFMA accumulator

DI float lrelu(float x, float s){ return x > 0.f ? x : s*x; }
DI float fastrcp(float x){ float r; asm("v_rcp_f32 %0, %1" : "=v"(r) : "v"(x)); return r; }
DI u16 f2bu(float f){ uint32 u = __float_as_uint(f); return (u16)((u + 0x7FFFu + ((u>>16)&1u)) >> 16); }
DI float b16f(u16 u){ return __uint_as_float(((uint32)u)<<16); }

// branch-free gelu (erf via Abramowitz-Stegun 7.1.26, |eps|<=1.5e-7)
DI float gelu_f(float x){
  const float z = fabsf(x) * 0.70710678118654752f;
  const float t = fastrcp(1.f + 0.3275911f*z);
  float p = 1.061405429f;
  p = p*t - 1.453152027f;
  p = p*t + 1.421413741f;
  p = p*t - 0.284496736f;
  p = p*t + 0.254829592f;
  p = p*t;
  const float e = __expf(-z*z);
  float er = 1.f - p*e;
  er = copysignf(er, x);
  return 0.5f*x*(1.f + er);
}

DI f4v mfma16(s8v a, s8v b, f4v c){
  return __builtin_amdgcn_mfma_f32_16x16x32_bf16(a, b, c, 0, 0, 0);
}

constexpr int NNODE = 50;
constexpr int NT = 512;
constexpr int SCS = 268;   // sc row stride (f32), %4==0 so bf16 sub-blocks stay 16B-aligned.
// G1 phase: cols 0..255 features, 256/257 es h0/h1, 258/259 ed h0/h1, 260..265 weights
// G2 phase: cols 0..127 features, 128 es, 129 ed, 130..132 weights, 140..203 = A3 bf16 [128]

// d_ws layout (u16 units):
constexpr int WS1  = 0;       // W1x^T [272][64]: rows 0..255 W1^T (h0|h1), 256..259 score folds, 260+ zero
constexpr int WS2  = 17408;   // [144][256]: rows 0..127 W2^T, 128 es2 fold, 129 ed2 fold, 130+ zero
constexpr int WSA1 = 54272;   // aw1^T [128][128]
constexpr int WSA2 = 70656;   // aw2^T [128][128]
constexpr int WSA3 = 87040;   // aw3^T padded [16][128]
constexpr int WSTOT= 89088;   // * 2 bytes

__global__ __launch_bounds__(256)
void ac_prep(const float* __restrict__ w1, const float* __restrict__ as1, const float* __restrict__ ad1,
             const float* __restrict__ w2, const float* __restrict__ as2, const float* __restrict__ ad2,
             const float* __restrict__ aw1, const float* __restrict__ aw2, const float* __restrict__ aw3,
             u16* __restrict__ ws)
{
  const int T1 = 272*64, T2 = 144*256, T3 = 128*128;
  for (int t = blockIdx.x*blockDim.x + threadIdx.x; t < WSTOT; t += gridDim.x*blockDim.x){
    float v; int o;
    if (t < T1){
      int n = t>>6, k = t&63;
      if (n < 256) v = w1[k*256 + n];
      else if (n < 260){
        int sd = (n-256)>>1, h = (n-256)&1;   // 256=es_h0 257=es_h1 258=ed_h0 259=ed_h1
        const float* av = (sd ? ad1 : as1) + h*128;
        const float* wr = w1 + k*256 + h*128;
        float s = 0.f;
        for (int c=0;c<128;++c) s += wr[c]*av[c];
        v = s;
      } else v = 0.f;
      o = WS1 + n*64 + k;
    } else if (t < T1+T2){
      int j = t - T1, n = j>>8, k = j&255;
      if (n < 128) v = w2[k*128 + n];
      else if (n < 130){
        const float* av = (n==129) ? ad2 : as2;
        const float* wr = w2 + k*128;
        float s = 0.f;
        for (int c=0;c<128;++c) s += wr[c]*av[c];
        v = s;
      } else v = 0.f;
      o = WS2 + n*256 + k;
    } else if (t < T1+T2+T3){
      int j = t - T1 - T2, n = j>>7, k = j&127;
      v = aw1[k*128 + n];
      o = WSA1 + n*128 + k;
    } else if (t < T1+T2+2*T3){
      int j = t - T1 - T2 - T3, n = j>>7, k = j&127;
      v = aw2[k*128 + n];
      o = WSA2 + n*128 + k;
    } else {
      int j = t - T1 - T2 - 2*T3, m = j>>7, k = j&127;
      v = (m < 4) ? aw3[k*4 + m] : 0.f;
      o = WSA3 + m*128 + k;
    }
    ws[o] = f2bu(v);
  }
}

// LDS map (20,056 f32 = 80,224 B; 2 blocks/CU):
//  pA2 u16[12800] @ f0      : A2 [50][256] (att1->G2). Overlays: A4 [50][128] @ f0 (G3 out,
//                             A2 dead), A5 [50][128] @ f3200 (G4 out).
//  sc  f32 [50][268] @ f6400 : per-wave column-sliced staging + scores/weights + A3 @ cols 140..203
//  geb f32[128] @ f19800 ; vh1 f32[128] @ f19928
//
// Wave-local fusion invariants:
//  * every wave redundantly computes the score tiles (A-fragments are lane-identical across
//    waves -> bitwise-identical results -> shared-column writes are benign same-value races)
//  * each wave reads ONLY columns it wrote inside a fused phase; ordering is wave-internal
//    (explicit lgkmcnt(0) + sched_barrier per rule: asm waitcnt needs sched fence)
//  * 4 block barriers total: after G1+att1, after G2+att2, after G3, after G4.
// NO min-waves hints (R5/R7 spilled); manual f2bu/asm-rcp helpers (R11-proven 76-VGPR codegen).

__global__ __launch_bounds__(NT)
void ac_main(const float* __restrict__ state,
             const float* __restrict__ b1, const float* __restrict__ b2,
             const float* __restrict__ ab1, const float* __restrict__ ab2,
             const float* __restrict__ ab3,
             const float* __restrict__ vw1, const float* __restrict__ vb1,
             const float* __restrict__ vw2, const float* __restrict__ vb2,
             const float* __restrict__ vw3, const float* __restrict__ vb3,
             const u16* __restrict__ ws,
             float* __restrict__ out_mean, float* __restrict__ out_val)
{
  __shared__ __align__(16) float sm[20056];
  u16*   pA2 = (u16*)sm;
  u16*   pA4 = (u16*)sm;            // G3 out (A2 dead after G2+att2 barrier)
  u16*   pA5 = (u16*)(sm + 3200);   // G4 out
  float* sc  = sm + 6400;
  float* geb = sm + 19800;
  float* vh1 = sm + 19928;

  const int tid = threadIdx.x, b = blockIdx.x;
  const int wid = tid>>6, l15 = tid&15, g = (tid>>4)&3;
  const int lan = tid & 63, lc = lan & 15, lq = lan >> 4;

  // ---- A-fragments of state straight from global (rows >=50 -> zero) ----
  s8v aS[4][2];
  {
    const float* xb = state + (size_t)b * (NNODE*64);
    #pragma unroll
    for (int mt=0;mt<4;++mt){
      const int row = mt*16 + l15;
      #pragma unroll
      for (int ks=0;ks<2;++ks){
        union { s8v v; u16 u[8]; } fr;
        if (mt < 3 || row < NNODE){
          const float* p = xb + row*64 + ks*32 + g*8;
          const float4 f0 = *(const float4*)(p);
          const float4 f1 = *(const float4*)(p + 4);
          fr.u[0]=f2bu(f0.x); fr.u[1]=f2bu(f0.y); fr.u[2]=f2bu(f0.z); fr.u[3]=f2bu(f0.w);
          fr.u[4]=f2bu(f1.x); fr.u[5]=f2bu(f1.y); fr.u[6]=f2bu(f1.z); fr.u[7]=f2bu(f1.w);
        } else {
          fr.u[0]=fr.u[1]=fr.u[2]=fr.u[3]=fr.u[4]=fr.u[5]=fr.u[6]=fr.u[7]=0;
        }
        aS[mt][ks] = fr.v;
      }
    }
  }

  // ================= fused G1 + att1 (wave-local; no barrier inside) =================
  // wave w: feature tiles nt = w, w+8 ; score tile nt = 16 (redundant, all waves)
  #pragma unroll
  for (int tt=0; tt<3; ++tt){
    const int nt = (tt < 2) ? (wid + tt*8) : 16;
    f4v acc[4];
    #pragma unroll
    for (int mt=0;mt<4;++mt) acc[mt] = (f4v){0.f,0.f,0.f,0.f};
    #pragma unroll
    for (int ks=0;ks<2;++ks){
      s8v bf = *(const s8v*)(ws + WS1 + (nt*16 + l15)*64 + ks*32 + g*8);
      #pragma unroll
      for (int mt=0;mt<4;++mt) acc[mt] = mfma16(aS[mt][ks], bf, acc[mt]);
    }
    const int col = nt*16 + l15;
    if (col < 260){
      #pragma unroll
      for (int mt=0;mt<4;++mt){
        #pragma unroll
        for (int r=0;r<4;++r){
          const int row = mt*16 + g*4 + r;
          if (mt < 3 || row < NNODE) sc[row*SCS + col] = acc[mt][r];
        }
      }
    }
  }
  asm volatile("s_waitcnt lgkmcnt(0)" ::: "memory");
  __builtin_amdgcn_sched_barrier(0);

  // att1 weights, both heads (per-wave over all rows; cross-wave same-value writes benign)
  if (lan < NNODE){
    const int i = lan;
    #pragma unroll
    for (int h=0;h<2;++h){
      const float edi = sc[i*SCS + 258 + h];
      const float eS = __expf(lrelu(sc[i*SCS + 256 + h] + edi, 0.2f));
      const float eL = (i > 0)       ? __expf(lrelu(sc[(i-1)*SCS + 256 + h] + edi, 0.2f)) : 0.f;
      const float eR = (i < NNODE-1) ? __expf(lrelu(sc[(i+1)*SCS + 256 + h] + edi, 0.2f)) : 0.f;
      const float rs = fastrcp(eL + eS + eR);
      sc[i*SCS + 260 + h*3    ] = eL*rs;
      sc[i*SCS + 260 + h*3 + 1] = eS*rs;
      sc[i*SCS + 260 + h*3 + 2] = eR*rs;
    }
  }
  asm volatile("s_waitcnt lgkmcnt(0)" ::: "memory");
  __builtin_amdgcn_sched_barrier(0);

  // att1 cells: wave-own column slices (2 blocks of 16 cols x 50 rows) -> A2
  {
    const int i0 = lq*13, i1 = (i0+13 < NNODE) ? i0+13 : NNODE;
    #pragma unroll
    for (int cb=0; cb<2; ++cb){
      const int col = (wid + cb*8)*16 + lc;
      const int wc = 260 + (col >> 7)*3;
      const float bj = b1[col];
      float pv  = (i0 > 0) ? sc[(i0-1)*SCS + col] : 0.f;
      float cur = sc[i0*SCS + col];
      #pragma unroll 4
      for (int i=i0; i<i1; ++i){
        const float nx = (i < NNODE-1) ? sc[(i+1)*SCS + col] : 0.f;
        const float wL = sc[i*SCS + wc], wS = sc[i*SCS + wc+1], wR = sc[i*SCS + wc+2];
        const float v = gelu_f(wL*pv + wS*cur + wR*nx + bj);
        pA2[i*256 + (col ^ ((i&7)<<3))] = f2bu(v);
        pv = cur; cur = nx;
      }
    }
  }
  __syncthreads();   // B1: A2 complete

  // ================= fused G2 + att2 (wave-local) =================
  // wave w: feature tile nt = w ; score tile nt = 8 (redundant)
  #pragma unroll
  for (int tt=0; tt<2; ++tt){
    const int nt = tt ? 8 : wid;
    f4v acc[4];
    #pragma unroll
    for (int mt=0;mt<4;++mt) acc[mt] = (f4v){0.f,0.f,0.f,0.f};
    #pragma unroll
    for (int ks=0;ks<8;++ks){
      s8v bf = *(const s8v*)(ws + WS2 + (nt*16 + l15)*256 + ks*32 + g*8);
      #pragma unroll
      for (int mt=0;mt<4;++mt){
        const int row = mt*16 + l15, c = ks*32 + g*8;
        s8v a = *(const s8v*)(pA2 + row*256 + (c ^ ((row&7)<<3)));
        acc[mt] = mfma16(a, bf, acc[mt]);
      }
    }
    const int col = nt*16 + l15;
    if (col < 130){
      #pragma unroll
      for (int mt=0;mt<4;++mt){
        #pragma unroll
        for (int r=0;r<4;++r){
          const int row = mt*16 + g*4 + r;
          if (mt < 3 || row < NNODE) sc[row*SCS + col] = acc[mt][r];
        }
      }
    }
  }
  asm volatile("s_waitcnt lgkmcnt(0)" ::: "memory");
  __builtin_amdgcn_sched_barrier(0);

  // att2 weights
  if (lan < NNODE){
    const int i = lan;
    const float edi = sc[i*SCS + 129];
    const float eS = __expf(lrelu(sc[i*SCS + 128] + edi, 0.2f));
    const float eL = (i > 0)       ? __expf(lrelu(sc[(i-1)*SCS + 128] + edi, 0.2f)) : 0.f;
    const float eR = (i < NNODE-1) ? __expf(lrelu(sc[(i+1)*SCS + 128] + edi, 0.2f)) : 0.f;
    const float rs = fastrcp(eL + eS + eR);
    sc[i*SCS + 130] = eL*rs;
    sc[i*SCS + 131] = eS*rs;
    sc[i*SCS + 132] = eR*rs;
  }
  asm volatile("s_waitcnt lgkmcnt(0)" ::: "memory");
  __builtin_amdgcn_sched_barrier(0);

  // att2 cells: wave-own 16 cols -> A3 (sc cols 140..203) ; in-wave pool reduce -> geb
  {
    const int col = wid*16 + lc;
    const int i0 = lq*13, i1 = (i0+13 < NNODE) ? i0+13 : NNODE;
    const float bj = b2[col];
    float ps = 0.f;
    float pv  = (i0 > 0) ? sc[(i0-1)*SCS + col] : 0.f;
    float cur = sc[i0*SCS + col];
    #pragma unroll 4
    for (int i=i0; i<i1; ++i){
      const float nx = (i < NNODE-1) ? sc[(i+1)*SCS + col] : 0.f;
      const float wL = sc[i*SCS + 130], wS = sc[i*SCS + 131], wR = sc[i*SCS + 132];
      const float v = gelu_f(wL*pv + wS*cur + wR*nx + bj);
      ((u16*)(sc + i*SCS + 140))[col ^ ((i&7)<<3)] = f2bu(v);
      ps += v;
      pv = cur; cur = nx;
    }
    ps += __shfl_xor(ps, 16);
    ps += __shfl_xor(ps, 32);
    if (lq == 0) geb[col] = ps * 0.02f;
  }
  __syncthreads();   // B2: A3 + geb complete

  // ---- G3: C = A3 x aw1^T ; lrelu+pack -> A4 (pA4; A2 region dead) ----
  {
    const int nt = wid;
    const s8v zv = {0,0,0,0,0,0,0,0};
    f4v acc[4];
    #pragma unroll
    for (int mt=0;mt<4;++mt) acc[mt] = (f4v){0.f,0.f,0.f,0.f};
    #pragma unroll
    for (int ks=0;ks<4;++ks){
      s8v bf = *(const s8v*)(ws + WSA1 + (nt*16 + l15)*128 + ks*32 + g*8);
      #pragma unroll
      for (int mt=0;mt<4;++mt){
        const int row = mt*16 + l15, c = ks*32 + g*8;
        s8v a = zv;
        if (mt < 3 || row < NNODE)   // A3-in-sc rows>=50 would be OOB
          a = *(const s8v*)((const u16*)(sc + row*SCS + 140) + (c ^ ((row&7)<<3)));
        acc[mt] = mfma16(a, bf, acc[mt]);
      }
    }
    const int col = nt*16 + l15;
    const float bj = ab1[col];
    #pragma unroll
    for (int mt=0;mt<4;++mt){
      #pragma unroll
      for (int r=0;r<4;++r){
        const int row = mt*16 + g*4 + r;
        if (mt < 3 || row < NNODE){
          const float v = lrelu(acc[mt][r] + bj, 0.01f);
          pA4[row*128 + (col ^ ((row&7)<<3))] = f2bu(v);
        }
      }
    }
  }
  __syncthreads();   // B3

  // ---- G4: C = A4 x aw2^T ; lrelu(+ab2)+pack -> A5 ----
  {
    const int nt = wid;
    f4v acc[4];
    #pragma unroll
    for (int mt=0;mt<4;++mt) acc[mt] = (f4v){0.f,0.f,0.f,0.f};
    #pragma unroll
    for (int ks=0;ks<4;++ks){
      s8v bf = *(const s8v*)(ws + WSA2 + (nt*16 + l15)*128 + ks*32 + g*8);
      #pragma unroll
      for (int mt=0;mt<4;++mt){
        const int row = mt*16 + l15, c = ks*32 + g*8;
        s8v a = *(const s8v*)(pA4 + row*128 + (c ^ ((row&7)<<3)));
        acc[mt] = mfma16(a, bf, acc[mt]);
      }
    }
    const int col = nt*16 + l15;
    const float bj = ab2[col];
    #pragma unroll
    for (int mt=0;mt<4;++mt){
      #pragma unroll
      for (int r=0;r<4;++r){
        const int row = mt*16 + g*4 + r;
        if (mt < 3 || row < NNODE){
          const float v = lrelu(acc[mt][r] + bj, 0.01f);
          pA5[row*128 + (col ^ ((row&7)<<3))] = f2bu(v);
        }
      }
    }
  }
  __syncthreads();   // B4

  // ---- G5: actor L3 tiny MFMA (waves 0-3) ; value MLP (wave 4). No more barriers. ----
  if (wid < 4){
    const int mt = wid;
    f4v acc = (f4v){0.f,0.f,0.f,0.f};
    #pragma unroll
    for (int ks=0;ks<4;++ks){
      s8v bf = *(const s8v*)(ws + WSA3 + l15*128 + ks*32 + g*8);
      const int row = mt*16 + l15, c = ks*32 + g*8;
      s8v a = *(const s8v*)(pA5 + row*128 + (c ^ ((row&7)<<3)));
      acc = mfma16(a, bf, acc);
    }
    if (l15 < 4){
      const float bj = ab3[l15];
      #pragma unroll
      for (int r=0;r<4;++r){
        const int row = mt*16 + g*4 + r;
        if (row < NNODE) out_mean[(size_t)b*200 + row*4 + l15] = acc[r] + bj;
      }
    }
  } else if (wid == 4){
    const int j = lan;
    float a0=0.f, a1=0.f;
    #pragma unroll 4
    for (int k=0;k<128;++k){
      const float gk = geb[k];
      a0 += gk*vw1[k*128 + j];
      a1 += gk*vw1[k*128 + j + 64];
    }
    vh1[j]      = lrelu(a0 + vb1[j],    0.01f);
    vh1[j + 64] = lrelu(a1 + vb1[j+64], 0.01f);
    asm volatile("s_waitcnt lgkmcnt(0)" ::: "memory");
    __builtin_amdgcn_sched_barrier(0);
    float c0=0.f, c1=0.f;
    #pragma unroll 4
    for (int k=0;k<128;++k){
      const float hk = vh1[k];
      c0 += hk*vw2[k*128 + j];
      c1 += hk*vw2[k*128 + j + 64];
    }
    const float va = lrelu(c0 + vb2[j],    0.01f);
    const float vb = lrelu(c1 + vb2[j+64], 0.01f);
    float p = va*vw3[j] + vb*vw3[j+64];
    #pragma unroll
    for (int off=32; off>0; off>>=1) p += __shfl_down(p, off);
    if (j == 0) out_val[b] = p + vb3[0];
  }
}

extern "C" void kernel_launch(void* const* d_in, const int* in_sizes, int n_in,
                              void* d_out, int out_size, void* d_ws, size_t ws_size,
                              hipStream_t stream)
{
  const float* state = (const float*)d_in[0];
  const float* w1    = (const float*)d_in[1];
  const float* as1   = (const float*)d_in[2];
  const float* ad1   = (const float*)d_in[3];
  const float* b1_   = (const float*)d_in[4];
  const float* w2    = (const float*)d_in[5];
  const float* as2   = (const float*)d_in[6];
  const float* ad2   = (const float*)d_in[7];
  const float* b2_   = (const float*)d_in[8];
  const float* aw1   = (const float*)d_in[9];
  const float* ab1   = (const float*)d_in[10];
  const float* aw2   = (const float*)d_in[11];
  const float* ab2   = (const float*)d_in[12];
  const float* aw3   = (const float*)d_in[13];
  const float* ab3   = (const float*)d_in[14];
  const float* vw1   = (const float*)d_in[15];
  const float* vb1   = (const float*)d_in[16];
  const float* vw2   = (const float*)d_in[17];
  const float* vb2   = (const float*)d_in[18];
  const float* vw3   = (const float*)d_in[19];
  const float* vb3   = (const float*)d_in[20];

  const int B = in_sizes[0] / (NNODE * 64);   // 2048
  float* out_mean = (float*)d_out;
  float* out_val  = out_mean + (size_t)B * 200;
  u16* ws = (u16*)d_ws;

  ac_prep<<<128, 256, 0, stream>>>(w1, as1, ad1, w2, as2, ad2, aw1, aw2, aw3, ws);
  ac_main<<<B, NT, 0, stream>>>(state, b1_, b2_, ab1, ab2, ab3,
                                vw1, vb1, vw2, vb2, vw3, vb3,
                                ws, out_mean, out_val);
}

// Round 16
// 154.768 us; speedup vs baseline: 1.1551x; 1.1551x over previous
//
#include <hip/hip_runtime.h>

#define DI __device__ __forceinline__

typedef unsigned int uint32;
typedef unsigned short u16;
typedef __attribute__((ext_vector_type(8))) short s8v;   // 8 bf16 (4 VGPR)
typedef __attribute__((ext_vector_type(4))) float f4v;   // MFMA accumulator

DI float lrelu(float x, float s){ return x > 0.f ? x : s*x; }
DI float fastrcp(float x){ float r; asm("v_rcp_f32 %0, %1" : "=v"(r) : "v"(x)); return r; }
DI u16 f2bu(float f){ uint32 u = __float_as_uint(f); return (u16)((u + 0x7FFFu + ((u>>16)&1u)) >> 16); }
DI float b16f(u16 u){ return __uint_as_float(((uint32)u)<<16); }

// branch-free gelu (erf via Abramowitz-Stegun 7.1.26, |eps|<=1.5e-7)
DI float gelu_f(float x){
  const float z = fabsf(x) * 0.70710678118654752f;
  const float t = fastrcp(1.f + 0.3275911f*z);
  float p = 1.061405429f;
  p = p*t - 1.453152027f;
  p = p*t + 1.421413741f;
  p = p*t - 0.284496736f;
  p = p*t + 0.254829592f;
  p = p*t;
  const float e = __expf(-z*z);
  float er = 1.f - p*e;
  er = copysignf(er, x);
  return 0.5f*x*(1.f + er);
}

DI f4v mfma16(s8v a, s8v b, f4v c){
  return __builtin_amdgcn_mfma_f32_16x16x32_bf16(a, b, c, 0, 0, 0);
}

constexpr int NNODE = 50;
constexpr int NT = 512;
constexpr int SCS = 268;   // sc row stride (f32), %4==0 -> bf16 A3 block 16B-aligned
// G1 phase: cols 0..255 features, 256/257 es h0/h1, 258/259 ed h0/h1, 260..265 weights
// G2 phase: cols 0..127 features, 128 es, 129 ed, 130..132 weights, 140..203 A3 bf16[128]

// d_ws layout (u16 units):
constexpr int WS1  = 0;       // W1x^T [272][64]: rows 0..255 W1^T (h0|h1), 256..259 score folds, 260+ zero
constexpr int WS2  = 17408;   // [144][256]: rows 0..127 W2^T, 128 es2 fold, 129 ed2 fold, 130+ zero
constexpr int WSA1 = 54272;   // aw1^T [128][128]
constexpr int WSA2 = 70656;   // aw2^T [128][128]
constexpr int WSA3 = 87040;   // aw3^T padded [16][128]
constexpr int WSTOT= 89088;   // * 2 bytes

__global__ __launch_bounds__(256)
void ac_prep(const float* __restrict__ w1, const float* __restrict__ as1, const float* __restrict__ ad1,
             const float* __restrict__ w2, const float* __restrict__ as2, const float* __restrict__ ad2,
             const float* __restrict__ aw1, const float* __restrict__ aw2, const float* __restrict__ aw3,
             u16* __restrict__ ws)
{
  const int T1 = 272*64, T2 = 144*256, T3 = 128*128;
  for (int t = blockIdx.x*blockDim.x + threadIdx.x; t < WSTOT; t += gridDim.x*blockDim.x){
    float v; int o;
    if (t < T1){
      int n = t>>6, k = t&63;
      if (n < 256) v = w1[k*256 + n];
      else if (n < 260){
        int sd = (n-256)>>1, h = (n-256)&1;   // 256=es_h0 257=es_h1 258=ed_h0 259=ed_h1
        const float* av = (sd ? ad1 : as1) + h*128;
        const float* wr = w1 + k*256 + h*128;
        float s = 0.f;
        for (int c=0;c<128;++c) s += wr[c]*av[c];
        v = s;
      } else v = 0.f;
      o = WS1 + n*64 + k;
    } else if (t < T1+T2){
      int j = t - T1, n = j>>8, k = j&255;
      if (n < 128) v = w2[k*128 + n];
      else if (n < 130){
        const float* av = (n==129) ? ad2 : as2;
        const float* wr = w2 + k*128;
        float s = 0.f;
        for (int c=0;c<128;++c) s += wr[c]*av[c];
        v = s;
      } else v = 0.f;
      o = WS2 + n*256 + k;
    } else if (t < T1+T2+T3){
      int j = t - T1 - T2, n = j>>7, k = j&127;
      v = aw1[k*128 + n];
      o = WSA1 + n*128 + k;
    } else if (t < T1+T2+2*T3){
      int j = t - T1 - T2 - T3, n = j>>7, k = j&127;
      v = aw2[k*128 + n];
      o = WSA2 + n*128 + k;
    } else {
      int j = t - T1 - T2 - 2*T3, m = j>>7, k = j&127;
      v = (m < 4) ? aw3[k*4 + m] : 0.f;
      o = WSA3 + m*128 + k;
    }
    ws[o] = f2bu(v);
  }
}

// LDS map (20,056 f32 = 80,224 B; 2 blocks/CU — VGPR-band-capped anyway):
//  pA2 u16[12800] @ f0   : A2 [50][256] (att1->G2). Overlays: pAs (state tile) @ f0
//                          (dead before att1 writes — all frag loads done by B1);
//                          pA4 [50][128] @ f0 (G3 out, A2 dead); pA5 @ f3200 (G4 out).
//  sc  f32 [50][268] @ f6400 : GEMM C staging + scores/weights + A3 bf16 @ cols 140..203
//  geb f32[128] @ f19800 ; vh1 f32[128] @ f19928
// Barriers (6): B0 stage, B1 G1, B2 att1, B3 fused G2+att2, B4 G3, B5 G4.
// Fused G2+att2: every wave redundantly computes the nt=8 score tile (bitwise-identical
// -> same-value LDS races benign); att2 is then wave-local (own cols, own weights),
// ordered by lgkmcnt(0)+sched_barrier; A3 goes to sc cols 140.. (disjoint from live A2);
// pool reduced in-wave via shfl_xor.
// NO min-waves hints (R5/R7 spilled); NO bf16-C epilogue (R8-R10: +16-20 VGPR);
// NO frag-from-global (R15: 8x redundant tile loads, -38us).

__global__ __launch_bounds__(NT)
void ac_main(const float* __restrict__ state,
             const float* __restrict__ b1, const float* __restrict__ b2,
             const float* __restrict__ ab1, const float* __restrict__ ab2,
             const float* __restrict__ ab3,
             const float* __restrict__ vw1, const float* __restrict__ vb1,
             const float* __restrict__ vw2, const float* __restrict__ vb2,
             const float* __restrict__ vw3, const float* __restrict__ vb3,
             const u16* __restrict__ ws,
             float* __restrict__ out_mean, float* __restrict__ out_val)
{
  __shared__ __align__(16) float sm[20056];
  u16*   pA2 = (u16*)sm;
  u16*   pAs = (u16*)sm;
  u16*   pA4 = (u16*)sm;            // G3 out (A2 dead after B3)
  u16*   pA5 = (u16*)(sm + 3200);   // G4 out
  float* sc  = sm + 6400;
  float* geb = sm + 19800;
  float* vh1 = sm + 19928;

  const int tid = threadIdx.x, b = blockIdx.x;
  const int wid = tid>>6, l15 = tid&15, g = (tid>>4)&3;
  const int lan = tid & 63, lc = lan & 15, lq = lan >> 4;

  // ---- P0: stage state -> pAs bf16 [50][64] swizzled (rows >=50 garbage; feeds
  //      only store-guarded C rows) ----
  {
    const float4* xb4 = (const float4*)(state + (size_t)b * (NNODE*64));
    for (int t = tid; t < 800; t += NT){
      float4 v = xb4[t];
      int i = t>>4, k0 = (t&15)*4;
      ushort4 u;
      u.x = f2bu(v.x); u.y = f2bu(v.y); u.z = f2bu(v.z); u.w = f2bu(v.w);
      *(ushort4*)(pAs + i*64 + (k0 ^ ((i&7)<<3))) = u;
    }
  }
  __syncthreads();   // B0

  // ---- A-fragments of state (regs). pAs dead after all waves' G1 MFMAs, i.e. by B1;
  //      first overwrite (att1 cells) is after B1. ----
  s8v aS[4][2];
  #pragma unroll
  for (int mt=0;mt<4;++mt)
    #pragma unroll
    for (int ks=0;ks<2;++ks){
      int row = mt*16 + l15, c = ks*32 + g*8;
      aS[mt][ks] = *(const s8v*)(pAs + row*64 + (c ^ ((row&7)<<3)));
    }

  // ---- G1 (both heads, one pass): C[50][260] = As x W1x^T -> sc ----
  for (int nt = wid; nt < 17; nt += 8){
    f4v acc[4];
    #pragma unroll
    for (int mt=0;mt<4;++mt) acc[mt] = (f4v){0.f,0.f,0.f,0.f};
    #pragma unroll
    for (int ks=0;ks<2;++ks){
      s8v bf = *(const s8v*)(ws + WS1 + (nt*16 + l15)*64 + ks*32 + g*8);
      #pragma unroll
      for (int mt=0;mt<4;++mt) acc[mt] = mfma16(aS[mt][ks], bf, acc[mt]);
    }
    const int col = nt*16 + l15;
    if (col < 260){
      #pragma unroll
      for (int mt=0;mt<4;++mt){
        #pragma unroll
        for (int r=0;r<4;++r){
          const int row = mt*16 + g*4 + r;
          if (mt < 3 || row < NNODE) sc[row*SCS + col] = acc[mt][r];
        }
      }
    }
  }
  __syncthreads();   // B1

  // ---- att1 weights (both heads; every wave computes same values — benign) ----
  if (lan < NNODE){
    const int i = lan;
    #pragma unroll
    for (int h=0;h<2;++h){
      const float edi = sc[i*SCS + 258 + h];
      const float eS = __expf(lrelu(sc[i*SCS + 256 + h] + edi, 0.2f));
      const float eL = (i > 0)       ? __expf(lrelu(sc[(i-1)*SCS + 256 + h] + edi, 0.2f)) : 0.f;
      const float eR = (i < NNODE-1) ? __expf(lrelu(sc[(i+1)*SCS + 256 + h] + edi, 0.2f)) : 0.f;
      const float rs = fastrcp(eL + eS + eR);
      sc[i*SCS + 260 + h*3    ] = eL*rs;
      sc[i*SCS + 260 + h*3 + 1] = eS*rs;
      sc[i*SCS + 260 + h*3 + 2] = eR*rs;
    }
  }
  asm volatile("s_waitcnt lgkmcnt(0)" ::: "memory");
  __builtin_amdgcn_sched_barrier(0);

  // ---- att1 cells: 2 row-strips x 256 cols, rotating feature registers -> A2 ----
  {
    const int q = tid>>8, j = tid&255;
    const int i0 = q*25, i1 = i0 + 25;
    const float bj = b1[j];
    const int wc = 260 + (j>>7)*3;
    float pv  = (i0 > 0) ? sc[(i0-1)*SCS + j] : 0.f;
    float cur = sc[i0*SCS + j];
    #pragma unroll 5
    for (int i = i0; i < i1; ++i){
      const float nx = (i < NNODE-1) ? sc[(i+1)*SCS + j] : 0.f;
      const float wL = sc[i*SCS + wc], wS = sc[i*SCS + wc + 1], wR = sc[i*SCS + wc + 2];
      const float v = gelu_f(wL*pv + wS*cur + wR*nx + bj);
      pA2[i*256 + (j ^ ((i&7)<<3))] = f2bu(v);
      pv = cur; cur = nx;
    }
  }
  __syncthreads();   // B2: A2 complete

  // ================= fused G2 + att2 (wave-local; no barrier inside) =================
  // wave w: feature tile nt = w ; score tile nt = 8 (redundant, all waves)
  #pragma unroll
  for (int tt=0; tt<2; ++tt){
    const int nt = tt ? 8 : wid;
    f4v acc[4];
    #pragma unroll
    for (int mt=0;mt<4;++mt) acc[mt] = (f4v){0.f,0.f,0.f,0.f};
    #pragma unroll
    for (int ks=0;ks<8;++ks){
      s8v bf = *(const s8v*)(ws + WS2 + (nt*16 + l15)*256 + ks*32 + g*8);
      #pragma unroll
      for (int mt=0;mt<4;++mt){
        const int row = mt*16 + l15, c = ks*32 + g*8;
        s8v a = *(const s8v*)(pA2 + row*256 + (c ^ ((row&7)<<3)));
        acc[mt] = mfma16(a, bf, acc[mt]);
      }
    }
    const int col = nt*16 + l15;
    if (col < 130){
      #pragma unroll
      for (int mt=0;mt<4;++mt){
        #pragma unroll
        for (int r=0;r<4;++r){
          const int row = mt*16 + g*4 + r;
          if (mt < 3 || row < NNODE) sc[row*SCS + col] = acc[mt][r];
        }
      }
    }
  }
  asm volatile("s_waitcnt lgkmcnt(0)" ::: "memory");
  __builtin_amdgcn_sched_barrier(0);

  // att2 weights (wave-local; reads own wave's redundant score writes)
  if (lan < NNODE){
    const int i = lan;
    const float edi = sc[i*SCS + 129];
    const float eS = __expf(lrelu(sc[i*SCS + 128] + edi, 0.2f));
    const float eL = (i > 0)       ? __expf(lrelu(sc[(i-1)*SCS + 128] + edi, 0.2f)) : 0.f;
    const float eR = (i < NNODE-1) ? __expf(lrelu(sc[(i+1)*SCS + 128] + edi, 0.2f)) : 0.f;
    const float rs = fastrcp(eL + eS + eR);
    sc[i*SCS + 130] = eL*rs;
    sc[i*SCS + 131] = eS*rs;
    sc[i*SCS + 132] = eR*rs;
  }
  asm volatile("s_waitcnt lgkmcnt(0)" ::: "memory");
  __builtin_amdgcn_sched_barrier(0);

  // att2 cells: wave-own 16 cols (written by this wave's feature tile) -> A3 in sc;
  // in-wave pool reduce -> geb
  {
    const int col = wid*16 + lc;
    const int i0 = lq*13, i1 = (i0+13 < NNODE) ? i0+13 : NNODE;
    const float bj = b2[col];
    float ps = 0.f;
    float pv  = (i0 > 0) ? sc[(i0-1)*SCS + col] : 0.f;
    float cur = sc[i0*SCS + col];
    #pragma unroll 4
    for (int i=i0; i<i1; ++i){
      const float nx = (i < NNODE-1) ? sc[(i+1)*SCS + col] : 0.f;
      const float wL = sc[i*SCS + 130], wS = sc[i*SCS + 131], wR = sc[i*SCS + 132];
      const float v = gelu_f(wL*pv + wS*cur + wR*nx + bj);
      ((u16*)(sc + i*SCS + 140))[col ^ ((i&7)<<3)] = f2bu(v);
      ps += v;
      pv = cur; cur = nx;
    }
    ps += __shfl_xor(ps, 16);
    ps += __shfl_xor(ps, 32);
    if (lq == 0) geb[col] = ps * 0.02f;
  }
  __syncthreads();   // B3: A3 + geb complete; A2 dead

  // ---- G3: C = A3 x aw1^T ; lrelu+pack -> A4 (pA4 @ f0) ----
  {
    const int nt = wid;
    const s8v zv = {0,0,0,0,0,0,0,0};
    f4v acc[4];
    #pragma unroll
    for (int mt=0;mt<4;++mt) acc[mt] = (f4v){0.f,0.f,0.f,0.f};
    #pragma unroll
    for (int ks=0;ks<4;++ks){
      s8v bf = *(const s8v*)(ws + WSA1 + (nt*16 + l15)*128 + ks*32 + g*8);
      #pragma unroll
      for (int mt=0;mt<4;++mt){
        const int row = mt*16 + l15, c = ks*32 + g*8;
        s8v a = zv;
        if (mt < 3 || row < NNODE)   // A3-in-sc rows>=50 would be OOB
          a = *(const s8v*)((const u16*)(sc + row*SCS + 140) + (c ^ ((row&7)<<3)));
        acc[mt] = mfma16(a, bf, acc[mt]);
      }
    }
    const int col = nt*16 + l15;
    const float bj = ab1[col];
    #pragma unroll
    for (int mt=0;mt<4;++mt){
      #pragma unroll
      for (int r=0;r<4;++r){
        const int row = mt*16 + g*4 + r;
        if (mt < 3 || row < NNODE){
          const float v = lrelu(acc[mt][r] + bj, 0.01f);
          pA4[row*128 + (col ^ ((row&7)<<3))] = f2bu(v);
        }
      }
    }
  }
  __syncthreads();   // B4

  // ---- G4: C = A4 x aw2^T ; lrelu(+ab2)+pack -> A5 (pA5 @ f3200) ----
  {
    const int nt = wid;
    f4v acc[4];
    #pragma unroll
    for (int mt=0;mt<4;++mt) acc[mt] = (f4v){0.f,0.f,0.f,0.f};
    #pragma unroll
    for (int ks=0;ks<4;++ks){
      s8v bf = *(const s8v*)(ws + WSA2 + (nt*16 + l15)*128 + ks*32 + g*8);
      #pragma unroll
      for (int mt=0;mt<4;++mt){
        const int row = mt*16 + l15, c = ks*32 + g*8;
        s8v a = *(const s8v*)(pA4 + row*128 + (c ^ ((row&7)<<3)));
        acc[mt] = mfma16(a, bf, acc[mt]);
      }
    }
    const int col = nt*16 + l15;
    const float bj = ab2[col];
    #pragma unroll
    for (int mt=0;mt<4;++mt){
      #pragma unroll
      for (int r=0;r<4;++r){
        const int row = mt*16 + g*4 + r;
        if (mt < 3 || row < NNODE){
          const float v = lrelu(acc[mt][r] + bj, 0.01f);
          pA5[row*128 + (col ^ ((row&7)<<3))] = f2bu(v);
        }
      }
    }
  }
  __syncthreads();   // B5

  // ---- G5: actor L3 tiny MFMA (waves 0-3) ; value MLP (wave 4). No more barriers. ----
  if (wid < 4){
    const int mt = wid;
    f4v acc = (f4v){0.f,0.f,0.f,0.f};
    #pragma unroll
    for (int ks=0;ks<4;++ks){
      s8v bf = *(const s8v*)(ws + WSA3 + l15*128 + ks*32 + g*8);
      const int row = mt*16 + l15, c = ks*32 + g*8;
      s8v a = *(const s8v*)(pA5 + row*128 + (c ^ ((row&7)<<3)));
      acc = mfma16(a, bf, acc);
    }
    if (l15 < 4){
      const float bj = ab3[l15];
      #pragma unroll
      for (int r=0;r<4;++r){
        const int row = mt*16 + g*4 + r;
        if (row < NNODE) out_mean[(size_t)b*200 + row*4 + l15] = acc[r] + bj;
      }
    }
  } else if (wid == 4){
    const int j = lan;
    float a0=0.f, a1=0.f;
    #pragma unroll 4
    for (int k=0;k<128;++k){
      const float gk = geb[k];
      a0 += gk*vw1[k*128 + j];
      a1 += gk*vw1[k*128 + j + 64];
    }
    vh1[j]      = lrelu(a0 + vb1[j],    0.01f);
    vh1[j + 64] = lrelu(a1 + vb1[j+64], 0.01f);
    asm volatile("s_waitcnt lgkmcnt(0)" ::: "memory");
    __builtin_amdgcn_sched_barrier(0);
    float c0=0.f, c1=0.f;
    #pragma unroll 4
    for (int k=0;k<128;++k){
      const float hk = vh1[k];
      c0 += hk*vw2[k*128 + j];
      c1 += hk*vw2[k*128 + j + 64];
    }
    const float va = lrelu(c0 + vb2[j],    0.01f);
    const float vb = lrelu(c1 + vb2[j+64], 0.01f);
    float p = va*vw3[j] + vb*vw3[j+64];
    #pragma unroll
    for (int off=32; off>0; off>>=1) p += __shfl_down(p, off);
    if (j == 0) out_val[b] = p + vb3[0];
  }
}

extern "C" void kernel_launch(void* const* d_in, const int* in_sizes, int n_in,
                              void* d_out, int out_size, void* d_ws, size_t ws_size,
                              hipStream_t stream)
{
  const float* state = (const float*)d_in[0];
  const float* w1    = (const float*)d_in[1];
  const float* as1   = (const float*)d_in[2];
  const float* ad1   = (const float*)d_in[3];
  const float* b1_   = (const float*)d_in[4];
  const float* w2    = (const float*)d_in[5];
  const float* as2   = (const float*)d_in[6];
  const float* ad2   = (const float*)d_in[7];
  const float* b2_   = (const float*)d_in[8];
  const float* aw1   = (const float*)d_in[9];
  const float* ab1   = (const float*)d_in[10];
  const float* aw2   = (const float*)d_in[11];
  const float* ab2   = (const float*)d_in[12];
  const float* aw3   = (const float*)d_in[13];
  const float* ab3   = (const float*)d_in[14];
  const float* vw1   = (const float*)d_in[15];
  const float* vb1   = (const float*)d_in[16];
  const float* vw2   = (const float*)d_in[17];
  const float* vb2   = (const float*)d_in[18];
  const float* vw3   = (const float*)d_in[19];
  const float* vb3   = (const float*)d_in[20];

  const int B = in_sizes[0] / (NNODE * 64);   // 2048
  float* out_mean = (float*)d_out;
  float* out_val  = out_mean + (size_t)B * 200;
  u16* ws = (u16*)d_ws;

  ac_prep<<<128, 256, 0, stream>>>(w1, as1, ad1, w2, as2, ad2, aw1, aw2, aw3, ws);
  ac_main<<<B, NT, 0, stream>>>(state, b1_, b2_, ab1, ab2, ab3,
                                vw1, vb1, vw2, vb2, vw3, vb3,
                                ws, out_mean, out_val);
}

// Round 17
// 140.568 us; speedup vs baseline: 1.2718x; 1.1010x over previous
//
#include <hip/hip_runtime.h>

#define DI __device__ __forceinline__

typedef unsigned int uint32;
typedef unsigned short u16;
typedef __attribute__((ext_vector_type(8))) short s8v;   // 8 bf16 (4 VGPR)
typedef __attribute__((ext_vector_type(4))) float f4v;   // MFMA accumulator

DI float lrelu(float x, float s){ return x > 0.f ? x : s*x; }
DI float fastrcp(float x){ float r; asm("v_rcp_f32 %0, %1" : "=v"(r) : "v"(x)); return r; }
DI u16 f2bu(float f){ uint32 u = __float_as_uint(f); return (u16)((u + 0x7FFFu + ((u>>16)&1u)) >> 16); }
DI float b16f(u16 u){ return __uint_as_float(((uint32)u)<<16); }

// branch-free gelu (erf via Abramowitz-Stegun 7.1.26, |eps|<=1.5e-7)
DI float gelu_f(float x){
  const float z = fabsf(x) * 0.70710678118654752f;
  const float t = fastrcp(1.f + 0.3275911f*z);
  float p = 1.061405429f;
  p = p*t - 1.453152027f;
  p = p*t + 1.421413741f;
  p = p*t - 0.284496736f;
  p = p*t + 0.254829592f;
  p = p*t;
  const float e = __expf(-z*z);
  float er = 1.f - p*e;
  er = copysignf(er, x);
  return 0.5f*x*(1.f + er);
}

DI f4v mfma16(s8v a, s8v b, f4v c){
  return __builtin_amdgcn_mfma_f32_16x16x32_bf16(a, b, c, 0, 0, 0);
}

constexpr int NNODE = 50;
constexpr int NT = 512;
constexpr int SCS = 266;   // sc row stride (f32).
// G1 (merged heads): cols 0..255 features, 256/257 = es h0/h1, 258/259 = ed h0/h1,
//                    260..262 = wL/wS/wR h0, 263..265 = h1
// G2: cols 0..127 features, 128=es, 129=ed, 130..132 = wL/wS/wR

// d_ws layout (u16 units):
constexpr int WS1  = 0;       // W1x^T [272][64]: rows 0..255 = W1^T (h0|h1), 256..259 = score folds, 260+ zero
constexpr int WS2  = 17408;   // [144][256]: rows 0..127 = W2^T, 128=es2 fold, 129=ed2 fold
constexpr int WSA1 = 54272;   // aw1^T [128][128]
constexpr int WSA2 = 70656;   // aw2^T [128][128]
constexpr int WSA3 = 87040;   // aw3^T padded [16][128]
constexpr int WSTOT= 89088;   // * 2 bytes

__global__ __launch_bounds__(256)
void ac_prep(const float* __restrict__ w1, const float* __restrict__ as1, const float* __restrict__ ad1,
             const float* __restrict__ w2, const float* __restrict__ as2, const float* __restrict__ ad2,
             const float* __restrict__ aw1, const float* __restrict__ aw2, const float* __restrict__ aw3,
             u16* __restrict__ ws)
{
  const int T1 = 272*64, T2 = 144*256, T3 = 128*128;
  for (int t = blockIdx.x*blockDim.x + threadIdx.x; t < WSTOT; t += gridDim.x*blockDim.x){
    float v; int o;
    if (t < T1){
      int n = t>>6, k = t&63;
      if (n < 256) v = w1[k*256 + n];
      else if (n < 260){
        int sd = (n-256)>>1, h = (n-256)&1;   // 256=es_h0 257=es_h1 258=ed_h0 259=ed_h1
        const float* av = (sd ? ad1 : as1) + h*128;
        const float* wr = w1 + k*256 + h*128;
        float s = 0.f;
        for (int c=0;c<128;++c) s += wr[c]*av[c];
        v = s;
      } else v = 0.f;
      o = WS1 + n*64 + k;
    } else if (t < T1+T2){
      int j = t - T1, n = j>>8, k = j&255;
      if (n < 128) v = w2[k*128 + n];
      else if (n < 130){
        const float* av = (n==129) ? ad2 : as2;
        const float* wr = w2 + k*128;
        float s = 0.f;
        for (int c=0;c<128;++c) s += wr[c]*av[c];
        v = s;
      } else v = 0.f;
      o = WS2 + n*256 + k;
    } else if (t < T1+T2+T3){
      int j = t - T1 - T2, n = j>>7, k = j&127;
      v = aw1[k*128 + n];
      o = WSA1 + n*128 + k;
    } else if (t < T1+T2+2*T3){
      int j = t - T1 - T2 - T3, n = j>>7, k = j&127;
      v = aw2[k*128 + n];
      o = WSA2 + n*128 + k;
    } else {
      int j = t - T1 - T2 - 2*T3, m = j>>7, k = j&127;
      v = (m < 4) ? aw3[k*4 + m] : 0.f;
      o = WSA3 + m*128 + k;
    }
    ws[o] = f2bu(v);
  }
}

// LDS map (19,828 f32 = 79,312 B -> block 79,360 B; 2 blocks/CU, VGPR-band-capped):
//  pAb  u16[12800] @ f0     : A2 [50][256] (att1->G2); A3/A5 [50][128] in first 6400 u16
//    overlays: pAs u16[4096] @ f0 (state tile, dead pre-att1); gebP f32[512] @ f3200
//              (A2 rows 25+, dead post-G2); vh1 f32[128] @ f3712 (G5)
//  sc   f32 [50][266] @ f6400 (G1..att2) ; overlay: pAb2 u16[6400] @ f6400 (A4, G3->G4)
//  geb  f32[128] @ f19700
//
// This is the measured-best configuration (R14: 140.8 us). Negative results locked in
// as constraints (do NOT retry):
//  * min-waves hints (waves_per_eu / launch_bounds 2nd arg): allocator force-squeezes
//    VGPR below need -> 78-389 MB scratch spill (R5/R7).
//  * bf16-C staging + multi-path epilogue: +16-20 VGPR regalloc bloat, slower at equal
//    occupancy (R8-R10).
//  * 3-kernel split (GAT / actor-head GEMM / value): x2 HBM round-trip + launch gaps eat
//    the tail win (R12/R13: 151-153 us).
//  * wave-local phase fusion w/ redundant score tiles: doubled A2 LDS scans + longer
//    per-wave serial chain > barrier saved (R15: 178.8, R16: 154.8).
//  * A-fragments direct from global: 8x redundant uncoalesced tile loads (R15).
// Occupancy is pinned at 16 waves/CU by the gfx950 VGPR band (65-128 regs -> 4 waves/SIMD,
// m69); escaping needs VGPR<=64 AND LDS<=54KB simultaneously — all measured paths there
// are net losses. Kernel is latency-bound: HBM 1.3%, VALU 33%, MFMA 6%.

__global__ __launch_bounds__(NT)
void ac_main(const float* __restrict__ state,
             const float* __restrict__ b1, const float* __restrict__ b2,
             const float* __restrict__ ab1, const float* __restrict__ ab2,
             const float* __restrict__ ab3,
             const float* __restrict__ vw1, const float* __restrict__ vb1,
             const float* __restrict__ vw2, const float* __restrict__ vb2,
             const float* __restrict__ vw3, const float* __restrict__ vb3,
             const u16* __restrict__ ws,
             float* __restrict__ out_mean, float* __restrict__ out_val)
{
  __shared__ __align__(16) float sm[19828];
  u16*   pAb  = (u16*)sm;
  u16*   pAs  = (u16*)sm;
  float* gebP = sm + 3200;
  float* vh1  = sm + 3712;
  float* sc   = sm + 6400;
  u16*   pAb2 = (u16*)(sm + 6400);
  float* geb  = sm + 19700;

  const int tid = threadIdx.x, b = blockIdx.x;
  const int wid = tid>>6, l15 = tid&15, g = (tid>>4)&3;

  // ---- P0: stage state -> pAs bf16 [50][64] swizzled (rows >=50 garbage; feeds
  //      only store-guarded C rows) ----
  {
    const float4* xb4 = (const float4*)(state + (size_t)b * (NNODE*64));
    for (int t = tid; t < 800; t += NT){
      float4 v = xb4[t];
      int i = t>>4, k0 = (t&15)*4;
      ushort4 u;
      u.x = f2bu(v.x); u.y = f2bu(v.y); u.z = f2bu(v.z); u.w = f2bu(v.w);
      *(ushort4*)(pAs + i*64 + (k0 ^ ((i&7)<<3))) = u;
    }
  }
  __syncthreads();

  // ---- A-fragments of state (regs). pAs dead after; first overwrite (att1 cells)
  //      is after the G1-end barrier. ----
  s8v aS[4][2];
  #pragma unroll
  for (int mt=0;mt<4;++mt)
    #pragma unroll
    for (int ks=0;ks<2;++ks){
      int row = mt*16 + l15, c = ks*32 + g*8;
      aS[mt][ks] = *(const s8v*)(pAs + row*64 + (c ^ ((row&7)<<3)));
    }

  // ---- G1 (BOTH heads, one pass): C[50][260] = As x W1x^T -> sc ----
  for (int nt = wid; nt < 17; nt += 8){
    f4v acc[4];
    #pragma unroll
    for (int mt=0;mt<4;++mt) acc[mt] = (f4v){0.f,0.f,0.f,0.f};
    #pragma unroll
    for (int ks=0;ks<2;++ks){
      s8v bf = *(const s8v*)(ws + WS1 + (nt*16 + l15)*64 + ks*32 + g*8);
      #pragma unroll
      for (int mt=0;mt<4;++mt) acc[mt] = mfma16(aS[mt][ks], bf, acc[mt]);
    }
    const int col = nt*16 + l15;
    if (col < 260){
      #pragma unroll
      for (int mt=0;mt<4;++mt){
        #pragma unroll
        for (int r=0;r<4;++r){
          const int row = mt*16 + g*4 + r;
          if (mt < 3 || row < NNODE) sc[row*SCS + col] = acc[mt][r];
        }
      }
    }
  }
  __syncthreads();

  // ---- att1 weights (both heads; every wave computes same values — benign) ----
  {
    const int i = tid & 63;
    if (i < NNODE){
      #pragma unroll
      for (int h=0;h<2;++h){
        const float edi = sc[i*SCS + 258 + h];
        const float eS = __expf(lrelu(sc[i*SCS + 256 + h] + edi, 0.2f));
        const float eL = (i > 0)       ? __expf(lrelu(sc[(i-1)*SCS + 256 + h] + edi, 0.2f)) : 0.f;
        const float eR = (i < NNODE-1) ? __expf(lrelu(sc[(i+1)*SCS + 256 + h] + edi, 0.2f)) : 0.f;
        const float rs = fastrcp(eL + eS + eR);
        sc[i*SCS + 260 + h*3    ] = eL*rs;
        sc[i*SCS + 260 + h*3 + 1] = eS*rs;
        sc[i*SCS + 260 + h*3 + 2] = eR*rs;
      }
    }
  }
  // ---- att1 cells: 2 row-strips x 256 cols, rotating feature registers -> A2 ----
  {
    const int q = tid>>8, j = tid&255, h = j>>7;
    const int i0 = q*25, i1 = i0 + 25;
    const float bj = b1[j];
    const int wc = 260 + h*3;
    float pv  = (i0 > 0) ? sc[(i0-1)*SCS + j] : 0.f;
    float cur = sc[i0*SCS + j];
    #pragma unroll 5
    for (int i = i0; i < i1; ++i){
      const float nx = (i < NNODE-1) ? sc[(i+1)*SCS + j] : 0.f;
      const float wL = sc[i*SCS + wc], wS = sc[i*SCS + wc + 1], wR = sc[i*SCS + wc + 2];
      const float v = gelu_f(wL*pv + wS*cur + wR*nx + bj);
      pAb[i*256 + (j ^ ((i&7)<<3))] = f2bu(v);
      pv = cur; cur = nx;
    }
  }
  __syncthreads();

  // ---- G2: C[50][130] = A2[.x256] x W2x^T -> sc ----
  for (int nt = wid; nt < 9; nt += 8){
    f4v acc[4];
    #pragma unroll
    for (int mt=0;mt<4;++mt) acc[mt] = (f4v){0.f,0.f,0.f,0.f};
    #pragma unroll
    for (int ks=0;ks<8;++ks){
      s8v bf = *(const s8v*)(ws + WS2 + (nt*16 + l15)*256 + ks*32 + g*8);
      #pragma unroll
      for (int mt=0;mt<4;++mt){
        const int row = mt*16 + l15, c = ks*32 + g*8;
        s8v a = *(const s8v*)(pAb + row*256 + (c ^ ((row&7)<<3)));
        acc[mt] = mfma16(a, bf, acc[mt]);
      }
    }
    const int col = nt*16 + l15;
    if (col < 130){
      #pragma unroll
      for (int mt=0;mt<4;++mt){
        #pragma unroll
        for (int r=0;r<4;++r){
          const int row = mt*16 + g*4 + r;
          if (mt < 3 || row < NNODE) sc[row*SCS + col] = acc[mt][r];
        }
      }
    }
  }
  __syncthreads();

  // ---- att2: weights then cells ; GELU -> A3 bf16 [50][128] ; pool partials ----
  {
    const int i = tid & 63;
    if (i < NNODE){
      const float edi = sc[i*SCS + 129];
      const float eS = __expf(lrelu(sc[i*SCS + 128] + edi, 0.2f));
      const float eL = (i > 0)       ? __expf(lrelu(sc[(i-1)*SCS + 128] + edi, 0.2f)) : 0.f;
      const float eR = (i < NNODE-1) ? __expf(lrelu(sc[(i+1)*SCS + 128] + edi, 0.2f)) : 0.f;
      const float rs = fastrcp(eL + eS + eR);
      sc[i*SCS + 130] = eL*rs;
      sc[i*SCS + 131] = eS*rs;
      sc[i*SCS + 132] = eR*rs;
    }
  }
  {
    const int q = tid>>7, j = tid&127;
    const int i0 = q*13, i1 = (i0+13 < NNODE) ? i0+13 : NNODE;
    const float bj = b2[j];
    float ps = 0.f;
    float pv  = (i0 > 0) ? sc[(i0-1)*SCS + j] : 0.f;
    float cur = sc[i0*SCS + j];
    #pragma unroll 4
    for (int i = i0; i < i1; ++i){
      const float nx = (i < NNODE-1) ? sc[(i+1)*SCS + j] : 0.f;
      const float wL = sc[i*SCS + 130], wS = sc[i*SCS + 131], wR = sc[i*SCS + 132];
      const float v = gelu_f(wL*pv + wS*cur + wR*nx + bj);
      pAb[i*128 + (j ^ ((i&7)<<3))] = f2bu(v);
      ps += v;
      pv = cur; cur = nx;
    }
    gebP[q*128 + j] = ps;
  }
  __syncthreads();

  // ---- G3: C = A3 x aw1^T ; fused lrelu+pack -> A4 (pAb2, on dead sc) ; geb finalize ----
  {
    const int nt = wid;
    f4v acc[4];
    #pragma unroll
    for (int mt=0;mt<4;++mt) acc[mt] = (f4v){0.f,0.f,0.f,0.f};
    #pragma unroll
    for (int ks=0;ks<4;++ks){
      s8v bf = *(const s8v*)(ws + WSA1 + (nt*16 + l15)*128 + ks*32 + g*8);
      #pragma unroll
      for (int mt=0;mt<4;++mt){
        const int row = mt*16 + l15, c = ks*32 + g*8;
        s8v a = *(const s8v*)(pAb + row*128 + (c ^ ((row&7)<<3)));
        acc[mt] = mfma16(a, bf, acc[mt]);
      }
    }
    const int col = nt*16 + l15;
    const float bj = ab1[col];
    #pragma unroll
    for (int mt=0;mt<4;++mt){
      #pragma unroll
      for (int r=0;r<4;++r){
        const int row = mt*16 + g*4 + r;
        if (mt < 3 || row < NNODE){
          const float v = lrelu(acc[mt][r] + bj, 0.01f);
          pAb2[row*128 + (col ^ ((row&7)<<3))] = f2bu(v);
        }
      }
    }
    if (tid < 128)
      geb[tid] = (gebP[tid] + gebP[128+tid] + gebP[256+tid] + gebP[384+tid]) * 0.02f;
  }
  __syncthreads();

  // ---- G4: C = A4 x aw2^T ; fused lrelu(+ab2)+pack -> A5 (pAb first half) ----
  {
    const int nt = wid;
    f4v acc[4];
    #pragma unroll
    for (int mt=0;mt<4;++mt) acc[mt] = (f4v){0.f,0.f,0.f,0.f};
    #pragma unroll
    for (int ks=0;ks<4;++ks){
      s8v bf = *(const s8v*)(ws + WSA2 + (nt*16 + l15)*128 + ks*32 + g*8);
      #pragma unroll
      for (int mt=0;mt<4;++mt){
        const int row = mt*16 + l15, c = ks*32 + g*8;
        s8v a = *(const s8v*)(pAb2 + row*128 + (c ^ ((row&7)<<3)));
        acc[mt] = mfma16(a, bf, acc[mt]);
      }
    }
    const int col = nt*16 + l15;
    const float bj = ab2[col];
    #pragma unroll
    for (int mt=0;mt<4;++mt){
      #pragma unroll
      for (int r=0;r<4;++r){
        const int row = mt*16 + g*4 + r;
        if (mt < 3 || row < NNODE){
          const float v = lrelu(acc[mt][r] + bj, 0.01f);
          pAb[row*128 + (col ^ ((row&7)<<3))] = f2bu(v);
        }
      }
    }
  }
  __syncthreads();

  // ---- G5: actor L3 via tiny MFMA (waves 0-3) ; value MLP (wave 4). No more barriers. ----
  if (wid < 4){
    const int mt = wid;
    f4v acc = (f4v){0.f,0.f,0.f,0.f};
    #pragma unroll
    for (int ks=0;ks<4;++ks){
      s8v bf = *(const s8v*)(ws + WSA3 + l15*128 + ks*32 + g*8);
      const int row = mt*16 + l15, c = ks*32 + g*8;
      s8v a = *(const s8v*)(pAb + row*128 + (c ^ ((row&7)<<3)));
      acc = mfma16(a, bf, acc);
    }
    if (l15 < 4){
      const float bj = ab3[l15];
      #pragma unroll
      for (int r=0;r<4;++r){
        const int row = mt*16 + g*4 + r;
        if (row < NNODE) out_mean[(size_t)b*200 + row*4 + l15] = acc[r] + bj;
      }
    }
  } else if (wid == 4){
    const int j = tid & 63;
    float a0=0.f, a1=0.f;
    #pragma unroll 4
    for (int k=0;k<128;++k){
      const float gk = geb[k];
      a0 += gk*vw1[k*128 + j];
      a1 += gk*vw1[k*128 + j + 64];
    }
    vh1[j]      = lrelu(a0 + vb1[j],    0.01f);
    vh1[j + 64] = lrelu(a1 + vb1[j+64], 0.01f);
    asm volatile("s_waitcnt lgkmcnt(0)" ::: "memory");
    __builtin_amdgcn_sched_barrier(0);
    float c0=0.f, c1=0.f;
    #pragma unroll 4
    for (int k=0;k<128;++k){
      const float hk = vh1[k];
      c0 += hk*vw2[k*128 + j];
      c1 += hk*vw2[k*128 + j + 64];
    }
    const float va = lrelu(c0 + vb2[j],    0.01f);
    const float vb = lrelu(c1 + vb2[j+64], 0.01f);
    float p = va*vw3[j] + vb*vw3[j+64];
    #pragma unroll
    for (int off=32; off>0; off>>=1) p += __shfl_down(p, off);
    if (j == 0) out_val[b] = p + vb3[0];
  }
}

extern "C" void kernel_launch(void* const* d_in, const int* in_sizes, int n_in,
                              void* d_out, int out_size, void* d_ws, size_t ws_size,
                              hipStream_t stream)
{
  const float* state = (const float*)d_in[0];
  const float* w1    = (const float*)d_in[1];
  const float* as1   = (const float*)d_in[2];
  const float* ad1   = (const float*)d_in[3];
  const float* b1_   = (const float*)d_in[4];
  const float* w2    = (const float*)d_in[5];
  const float* as2   = (const float*)d_in[6];
  const float* ad2   = (const float*)d_in[7];
  const float* b2_   = (const float*)d_in[8];
  const float* aw1   = (const float*)d_in[9];
  const float* ab1   = (const float*)d_in[10];
  const float* aw2   = (const float*)d_in[11];
  const float* ab2   = (const float*)d_in[12];
  const float* aw3   = (const float*)d_in[13];
  const float* ab3   = (const float*)d_in[14];
  const float* vw1   = (const float*)d_in[15];
  const float* vb1   = (const float*)d_in[16];
  const float* vw2   = (const float*)d_in[17];
  const float* vb2   = (const float*)d_in[18];
  const float* vw3   = (const float*)d_in[19];
  const float* vb3   = (const float*)d_in[20];

  const int B = in_sizes[0] / (NNODE * 64);   // 2048
  float* out_mean = (float*)d_out;
  float* out_val  = out_mean + (size_t)B * 200;
  u16* ws = (u16*)d_ws;

  ac_prep<<<128, 256, 0, stream>>>(w1, as1, ad1, w2, as2, ad2, aw1, aw2, aw3, ws);
  ac_main<<<B, NT, 0, stream>>>(state, b1_, b2_, ab1, ab2, ab3,
                                vw1, vb1, vw2, vb2, vw3, vb3,
                                ws, out_mean, out_val);
}